// Round 17
// baseline (173.039 us; speedup 1.0000x reference)
//
#include <hip/hip_runtime.h>
#include <hip/hip_fp16.h>
#include <math.h>

#define F_IN 128
#define C1 256   // HEADS*HID
#define NH1 4
#define C2 64
#define NSL 16   // bucket slots per (xcd, node)

typedef __attribute__((ext_vector_type(8))) _Float16 f16x8;
typedef __attribute__((ext_vector_type(4))) float f32x4;
typedef __attribute__((ext_vector_type(2))) float f32x2;

__device__ __forceinline__ float lrelu(float x) { return x >= 0.f ? x : 0.2f * x; }
__device__ __forceinline__ float elu(float x) { return x > 0.f ? x : expm1f(x); }
__device__ __forceinline__ int rli(int v, int j) { return __builtin_amdgcn_readlane(v, j); }

// packed 2xf32 FMA: acc += a * b (per 32-bit half)
__device__ __forceinline__ void pkfma(f32x2& acc, f32x2 a, f32x2 b) {
    asm("v_pk_fma_f32 %0, %1, %2, %0" : "+v"(acc) : "v"(a), "v"(b));
}

__device__ __forceinline__ int get_xcd() {
    int x;
    asm volatile("s_getreg_b32 %0, hwreg(HW_REG_XCC_ID)" : "=s"(x));
    return x & 7;
}

struct __align__(8) H4 { __half2 a, b; };

// per-lane (node d): merge 8 per-XCD segments -> src index for lane l (l>=1)
// cnt8 layout: [xcd][node] stride 4 ints; elist8: [xcd][node][NSL]
__device__ __forceinline__ int seg_lookup(const int* __restrict__ cnt8,
                                          const int* __restrict__ elist8,
                                          int d, int l, int N, int* lenOut) {
    int myc = 0;
    if (l < 8) {
        myc = cnt8[(size_t)l * ((size_t)N * 4) + (size_t)d * 4];
        if (myc > NSL) myc = NSL;
    }
    int q1 = rli(myc, 0);
    int q2 = q1 + rli(myc, 1);
    int q3 = q2 + rli(myc, 2);
    int q4 = q3 + rli(myc, 3);
    int q5 = q4 + rli(myc, 4);
    int q6 = q5 + rli(myc, 5);
    int q7 = q6 + rli(myc, 6);
    int q8 = q7 + rli(myc, 7);
    int len = q8 + 1; if (len > 64) len = 64;
    *lenOut = len;
    if (l == 0 || l >= len) return d;
    int e = l - 1;
    int seg = 0, off = e;
    if (e >= q1) { seg = 1; off = e - q1; }
    if (e >= q2) { seg = 2; off = e - q2; }
    if (e >= q3) { seg = 3; off = e - q3; }
    if (e >= q4) { seg = 4; off = e - q4; }
    if (e >= q5) { seg = 5; off = e - q5; }
    if (e >= q6) { seg = 6; off = e - q6; }
    if (e >= q7) { seg = 7; off = e - q7; }
    return elist8[(size_t)seg * ((size_t)N * NSL) + (size_t)d * NSL + off];
}

// ---------------- k_init: atS/atD (blocks 0-3) + cW = b2@Wc + bc (block 4) ----------------
__global__ __launch_bounds__(256) void k_init(const float* __restrict__ W1,
                                              const float* __restrict__ aS1,
                                              const float* __restrict__ aD1,
                                              const float* __restrict__ b2,
                                              const float* __restrict__ Wc,
                                              const float* __restrict__ bc,
                                              float* __restrict__ atS,
                                              float* __restrict__ atD,
                                              float* __restrict__ cW) {
    if (blockIdx.x < 4) {
        int t3 = blockIdx.x * 256 + threadIdx.x;
        bool isD = t3 >= 512;
        int r = t3 & 511;
        int h = r >> 7, k = r & 127;
        const float* a = isD ? aD1 : aS1;
        float s = 0.f;
        for (int c = 0; c < 64; ++c) s += W1[(size_t)k * C1 + h * 64 + c] * a[h * 64 + c];
        (isD ? atD : atS)[h * 128 + k] = s;
    } else if (threadIdx.x < 2) {
        int j = threadIdx.x;
        float s = bc[j];
        for (int c = 0; c < 64; ++c) s += b2[c] * Wc[c * 2 + j];
        cW[j] = s;
    }
}

// ---------------- k1: XCD-local bucketed edge pass ∥ W-prep ∥ x-prep ----------------
// Atomics are workgroup-scope -> performed in the local XCD L2 (no MALL round-trip).
// cnt8/elist8 partitioned per XCD (line-exclusive) so non-coherent L2s never share lines.
__global__ __launch_bounds__(256) void k_edges_prep(
    const int* __restrict__ esrc, const int* __restrict__ edst,
    int* __restrict__ cnt8, int* __restrict__ elist8, int E, int N,
    int countBlocks, int prepBlocks,
    const float* __restrict__ W1, const float* __restrict__ W2,
    __half* __restrict__ W1T, __half* __restrict__ W2T,
    const float* __restrict__ x, const float* __restrict__ atS,
    const float* __restrict__ atD, __half* __restrict__ xh,
    float* __restrict__ sS, float* __restrict__ sD) {
    int b = blockIdx.x;
    if (b < countBlocks) {
        int xcd = get_xcd();
        int* cntL = cnt8 + (size_t)xcd * ((size_t)N * 4);
        int* elL  = elist8 + (size_t)xcd * ((size_t)N * NSL);
        int base = b * 4096 + threadIdx.x;
        int sv[16], dv[16], pv[16];
#pragma unroll
        for (int k = 0; k < 16; ++k) {      // coalesced edge loads
            int e = base + k * 256;
            int ss = 0, dd = -1;
            if (e < E) { ss = esrc[e]; dd = edst[e]; }
            sv[k] = ss; dv[k] = dd;
        }
#pragma unroll
        for (int k = 0; k < 8; ++k)         // atomics group A (XCD-local L2)
            pv[k] = (dv[k] >= 0)
                ? __hip_atomic_fetch_add(&cntL[(size_t)dv[k] * 4], 1,
                                         __ATOMIC_RELAXED, __HIP_MEMORY_SCOPE_WORKGROUP)
                : NSL;
#pragma unroll
        for (int k = 8; k < 16; ++k)        // atomics group B (16 in flight)
            pv[k] = (dv[k] >= 0)
                ? __hip_atomic_fetch_add(&cntL[(size_t)dv[k] * 4], 1,
                                         __ATOMIC_RELAXED, __HIP_MEMORY_SCOPE_WORKGROUP)
                : NSL;
#pragma unroll
        for (int k = 0; k < 8; ++k)         // scatter A (B atomics still flying)
            if (dv[k] >= 0 && pv[k] < NSL) elL[(size_t)dv[k] * NSL + pv[k]] = sv[k];
#pragma unroll
        for (int k = 8; k < 16; ++k)        // scatter B
            if (dv[k] >= 0 && pv[k] < NSL) elL[(size_t)dv[k] * NSL + pv[k]] = sv[k];
    } else if (b < countBlocks + prepBlocks) {
        int tid = (b - countBlocks) * 256 + threadIdx.x;
        if (tid < F_IN * C1) {
            int k = tid >> 8, n = tid & 255;
            W1T[n * F_IN + k] = __float2half(W1[tid]);
        }
        int t2 = tid - F_IN * C1;
        if (t2 >= 0 && t2 < C1 * C2) {
            int k = t2 >> 6, n = t2 & 63;
            W2T[n * C1 + k] = __float2half(W2[t2]);
        }
    } else {
        int n = (b - countBlocks - prepBlocks) * 4 + (threadIdx.x >> 6);
        if (n >= N) return;
        int l = threadIdx.x & 63;
        float2 xv = *(const float2*)(x + (size_t)n * F_IN + l * 2);
        *(__half2*)(xh + (size_t)n * F_IN + l * 2) = __floats2half2_rn(xv.x, xv.y);
        float p[8];
#pragma unroll
        for (int h = 0; h < 4; ++h) {
            float2 a = *(const float2*)(atS + h * 128 + l * 2);
            float2 bb = *(const float2*)(atD + h * 128 + l * 2);
            p[h]     = xv.x * a.x + xv.y * a.y;
            p[4 + h] = xv.x * bb.x + xv.y * bb.y;
        }
#pragma unroll
        for (int off = 1; off < 64; off <<= 1) {
#pragma unroll
            for (int j = 0; j < 8; ++j) p[j] += __shfl_xor(p[j], off, 64);
        }
        if (l == 0) {
            *(float4*)(sS + n * 4) = make_float4(p[0], p[1], p[2], p[3]);
            *(float4*)(sD + n * 4) = make_float4(p[4], p[5], p[6], p[7]);
        }
    }
}

// ---------------- layer-1 aggregation in x-space, fused softmax (r7 structure) ----------------
__global__ __launch_bounds__(256) void k_aggr1(const int* __restrict__ elist8,
                                               const int* __restrict__ cnt8,
                                               const float* __restrict__ sS,
                                               const float* __restrict__ sD,
                                               const __half* __restrict__ xh,
                                               __half* __restrict__ agg, int N) {
    __shared__ __align__(16) float wA[4][64][8];   // {wx,wx,wy,wy,wz,wz,ww,ww}
    int wv = threadIdx.x >> 6, l = threadIdx.x & 63;
    int d = blockIdx.x * 4 + wv;
    if (d >= N) return;
    int len;
    int sl = seg_lookup(cnt8, elist8, d, l, N, &len);
    float4 sd4 = *(const float4*)(sD + d * 4);
    const __half* xb = xh + l * 2;
    f32x2 a0 = {0.f, 0.f}, a1 = {0.f, 0.f}, a2 = {0.f, 0.f}, a3 = {0.f, 0.f};
    float4 den = {0.f, 0.f, 0.f, 0.f};
    float4 w = {0.f, 0.f, 0.f, 0.f};
    if (l < len) {
        float4 s4 = *(const float4*)(sS + sl * 4);
        w.x = __expf(lrelu(s4.x + sd4.x));
        w.y = __expf(lrelu(s4.y + sd4.y));
        w.z = __expf(lrelu(s4.z + sd4.z));
        w.w = __expf(lrelu(s4.w + sd4.w));
        den.x = w.x; den.y = w.y; den.z = w.z; den.w = w.w;
    }
    *(float4*)&wA[wv][l][0] = make_float4(w.x, w.x, w.y, w.y);
    *(float4*)&wA[wv][l][4] = make_float4(w.z, w.z, w.w, w.w);
    __builtin_amdgcn_wave_barrier();   // in-wave LDS RAW ordering
    int jm = (len + 3) & ~3;           // zero-padded slots: branch-free
    for (int j = 0; j < jm; j += 4) {
#pragma unroll
        for (int u = 0; u < 4; ++u) {
            int s = rli(sl, j + u);
            f32x4 q0 = *(const f32x4*)&wA[wv][j + u][0];   // uniform broadcast
            f32x4 q1 = *(const f32x4*)&wA[wv][j + u][4];
            float2 f = __half22float2(*(const __half2*)(xb + ((size_t)(unsigned)s << 7)));
            f32x2 fv = {f.x, f.y};
            pkfma(a0, fv, f32x2{q0[0], q0[1]});
            pkfma(a1, fv, f32x2{q0[2], q0[3]});
            pkfma(a2, fv, f32x2{q1[0], q1[1]});
            pkfma(a3, fv, f32x2{q1[2], q1[3]});
        }
    }
#pragma unroll
    for (int off = 1; off < 64; off <<= 1) {
        den.x += __shfl_xor(den.x, off, 64);
        den.y += __shfl_xor(den.y, off, 64);
        den.z += __shfl_xor(den.z, off, 64);
        den.w += __shfl_xor(den.w, off, 64);
    }
    float i0 = 1.f / (den.x + 1e-16f), i1 = 1.f / (den.y + 1e-16f);
    float i2 = 1.f / (den.z + 1e-16f), i3 = 1.f / (den.w + 1e-16f);
    __half2* ag = (__half2*)(agg + (size_t)d * 512);
    ag[0 * 64 + l] = __floats2half2_rn(a0[0] * i0, a0[1] * i0);
    ag[1 * 64 + l] = __floats2half2_rn(a1[0] * i1, a1[1] * i1);
    ag[2 * 64 + l] = __floats2half2_rn(a2[0] * i2, a2[1] * i2);
    ag[3 * 64 + l] = __floats2half2_rn(a3[0] * i3, a3[1] * i3);
}

// ---------------- fused GEMM1 (per-head) + GEMM2 + classifier-projection z ----------------
__global__ __launch_bounds__(256) void k_gemm12(
    const __half* __restrict__ agg, const __half* __restrict__ W1T,
    const float* __restrict__ b1, const __half* __restrict__ W2T,
    const float* __restrict__ aS, const float* __restrict__ aD,
    const float* __restrict__ Wc,
    float* __restrict__ z2, float* __restrict__ sS, float* __restrict__ sD, int N) {
    __shared__ __align__(16) char smem[65536];
    __half* As  = (__half*)smem;             // [64][128] granule-swizzled (16KB)
    __half* Bs1 = (__half*)(smem + 16384);   // [64][128] (16KB)
    __half* Bs2 = (__half*)smem;             // [64][256] aliases As+Bs1 (32KB)
    __half* o1L = (__half*)(smem + 32768);   // [64][256] swizzled o1 tile (32KB)
    int t = threadIdx.x;
    int rowBase = blockIdx.x * 64;
    int lane = t & 63, wv = t >> 6;
    int lm = lane & 15, lk = lane >> 4;
    int rA = wv * 16 + lm;
    int row = rowBase + rA;

    // phase A: o1 = ELU(agg @ W1 + b1), one 64-col block per head
    for (int h = 0; h < 4; ++h) {
        __syncthreads();
        {   // stage As <- agg head h
            int r = t >> 2;
            const uint4* src = (const uint4*)(agg + (size_t)(rowBase + r) * 512 + h * 128);
#pragma unroll
            for (int j = 0; j < 4; ++j) {
                int g = (t & 3) * 4 + j;
                uint4 v = {0, 0, 0, 0};
                if (rowBase + r < N) v = src[g];
                *(uint4*)&As[r * 128 + (g ^ (r & 7)) * 8] = v;
            }
        }
        {   // stage Bs1 <- W1T rows h*64..+63
            int r = t >> 2;
            const uint4* src = (const uint4*)(W1T + (size_t)(h * 64 + r) * 128);
#pragma unroll
            for (int j = 0; j < 4; ++j) {
                int g = (t & 3) * 4 + j;
                *(uint4*)&Bs1[r * 128 + (g ^ (r & 7)) * 8] = src[g];
            }
        }
        __syncthreads();
        f32x4 acc[4];
#pragma unroll
        for (int nt = 0; nt < 4; ++nt) acc[nt] = f32x4{0.f, 0.f, 0.f, 0.f};
#pragma unroll
        for (int kt = 0; kt < 4; ++kt) {
            int gs = ((kt * 4 + lk) ^ (lm & 7)) * 8;
            f16x8 af = *(const f16x8*)&As[rA * 128 + gs];
#pragma unroll
            for (int nt = 0; nt < 4; ++nt) {
                f16x8 bf = *(const f16x8*)&Bs1[(nt * 16 + lm) * 128 + gs];
                acc[nt] = __builtin_amdgcn_mfma_f32_16x16x32_f16(bf, af, acc[nt], 0, 0, 0);
            }
        }
#pragma unroll
        for (int nt = 0; nt < 4; ++nt) {   // epilogue -> swizzled LDS tile
            int c = h * 64 + nt * 16 + lk * 4;
            float4 bb = *(const float4*)(b1 + c);
            H4 hv;
            hv.a = __floats2half2_rn(elu(acc[nt][0] + bb.x), elu(acc[nt][1] + bb.y));
            hv.b = __floats2half2_rn(elu(acc[nt][2] + bb.z), elu(acc[nt][3] + bb.w));
            int g = c >> 3;
            int gs2 = (g & ~7) | ((g & 7) ^ (rA & 7));
            *(H4*)((char*)o1L + rA * 512 + gs2 * 16 + (c & 7) * 2) = hv;
        }
    }
    __syncthreads();   // o1L complete; As/Bs1 consumers done
    {   // stage Bs2 <- W2T [64][256]
        int n = t & 63, gb = (t >> 6) * 8;
        const uint4* src = (const uint4*)(W2T + (size_t)n * C1);
#pragma unroll
        for (int j = 0; j < 8; ++j) {
            int g = gb + j;
            int gs = (g & ~7) | ((g & 7) ^ (n & 7));
            *(uint4*)&Bs2[n * 256 + gs * 8] = src[g];
        }
    }
    __syncthreads();

    // phase B: h2 = o1 @ W2 (K=256), fused scores + z = h2 @ Wc
    f32x4 acc2[4];
#pragma unroll
    for (int nt = 0; nt < 4; ++nt) acc2[nt] = f32x4{0.f, 0.f, 0.f, 0.f};
#pragma unroll
    for (int kt2 = 0; kt2 < 8; ++kt2) {
        int g = kt2 * 4 + lk;
        int gs = (g & ~7) | ((g & 7) ^ (lm & 7));   // rA&7 == lm&7
        f16x8 af = *(const f16x8*)&o1L[rA * 256 + gs * 8];
#pragma unroll
        for (int nt = 0; nt < 4; ++nt) {
            f16x8 bf = *(const f16x8*)&Bs2[(nt * 16 + lm) * 256 + gs * 8];
            acc2[nt] = __builtin_amdgcn_mfma_f32_16x16x32_f16(bf, af, acc2[nt], 0, 0, 0);
        }
    }
    float ps = 0.f, pd = 0.f, z0 = 0.f, z1 = 0.f;
#pragma unroll
    for (int nt = 0; nt < 4; ++nt) {
        int cbase = nt * 16 + lk * 4;
        float a0 = acc2[nt][0], a1 = acc2[nt][1], a2 = acc2[nt][2], a3 = acc2[nt][3];
        float4 s4 = *(const float4*)(aS + cbase);
        float4 d4 = *(const float4*)(aD + cbase);
        ps += a0 * s4.x + a1 * s4.y + a2 * s4.z + a3 * s4.w;
        pd += a0 * d4.x + a1 * d4.y + a2 * d4.z + a3 * d4.w;
        float4 w0 = *(const float4*)(Wc + cbase * 2);       // cols cbase, cbase+1
        float4 w1 = *(const float4*)(Wc + cbase * 2 + 4);   // cols cbase+2, cbase+3
        z0 += a0 * w0.x + a1 * w0.z + a2 * w1.x + a3 * w1.z;
        z1 += a0 * w0.y + a1 * w0.w + a2 * w1.y + a3 * w1.w;
    }
    ps += __shfl_xor(ps, 16, 64); ps += __shfl_xor(ps, 32, 64);
    pd += __shfl_xor(pd, 16, 64); pd += __shfl_xor(pd, 32, 64);
    z0 += __shfl_xor(z0, 16, 64); z0 += __shfl_xor(z0, 32, 64);
    z1 += __shfl_xor(z1, 16, 64); z1 += __shfl_xor(z1, 32, 64);
    if (lk == 0 && row < N) {
        sS[row] = ps; sD[row] = pd;
        *(float2*)(z2 + 2 * row) = make_float2(z0, z1);
    }
}

// ---------------- layer-2 aggregation on z (8B/edge) + fused classifier ----------------
__global__ __launch_bounds__(256) void k_aggr2(const int* __restrict__ elist8,
                                               const int* __restrict__ cnt8,
                                               const float* __restrict__ sS,
                                               const float* __restrict__ sD,
                                               const float* __restrict__ z2,
                                               const float* __restrict__ cW,
                                               float* __restrict__ out, int N) {
    int wv = threadIdx.x >> 6, l = threadIdx.x & 63;
    int d = blockIdx.x * 4 + wv;
    if (d >= N) return;
    int len;
    int sl = seg_lookup(cnt8, elist8, d, l, N, &len);
    float sdd = sD[d];
    float den = 0.f, nx = 0.f, ny = 0.f;
    if (l < len) {
        float2 z = *(const float2*)(z2 + 2 * sl);
        float w = __expf(lrelu(sS[sl] + sdd));
        den = w; nx = w * z.x; ny = w * z.y;
    }
#pragma unroll
    for (int off = 1; off < 64; off <<= 1) {
        den += __shfl_xor(den, off, 64);
        nx  += __shfl_xor(nx,  off, 64);
        ny  += __shfl_xor(ny,  off, 64);
    }
    if (l == 0) {
        float inv = 1.f / (den + 1e-16f);
        out[d * 2 + 0] = nx * inv + cW[0];
        out[d * 2 + 1] = ny * inv + cW[1];
    }
}

extern "C" void kernel_launch(void* const* d_in, const int* in_sizes, int n_in,
                              void* d_out, int out_size, void* d_ws, size_t ws_size,
                              hipStream_t stream) {
    const float* x   = (const float*)d_in[0];
    const int*   ei  = (const int*)d_in[1];
    const float* W1  = (const float*)d_in[2];
    const float* aS1 = (const float*)d_in[3];
    const float* aD1 = (const float*)d_in[4];
    const float* b1  = (const float*)d_in[5];
    const float* W2  = (const float*)d_in[6];
    const float* aS2 = (const float*)d_in[7];
    const float* aD2 = (const float*)d_in[8];
    const float* b2  = (const float*)d_in[9];
    const float* Wc  = (const float*)d_in[10];
    const float* bc  = (const float*)d_in[11];
    float* out = (float*)d_out;

    int N = in_sizes[0] / F_IN;
    int E = in_sizes[1] / 2;
    const int* esrc = ei;
    const int* edst = ei + E;

    char* p = (char*)d_ws;
    __half* agg  = (__half*)p; p += (size_t)N * 512 * sizeof(__half);
    __half* xh   = (__half*)p; p += (size_t)N * F_IN * sizeof(__half);
    float* z2    = (float*)p;  p += (size_t)N * 2 * sizeof(float);
    float* s1S   = (float*)p;  p += (size_t)N * NH1 * sizeof(float);
    float* s1D   = (float*)p;  p += (size_t)N * NH1 * sizeof(float);
    __half* W1T  = (__half*)p; p += (size_t)C1 * F_IN * sizeof(__half);
    __half* W2T  = (__half*)p; p += (size_t)C2 * C1 * sizeof(__half);
    float* atS   = (float*)p;  p += 512 * sizeof(float);
    float* atD   = (float*)p;  p += 512 * sizeof(float);
    float* cW    = (float*)p;  p += 2 * sizeof(float);
    float* s2S   = (float*)p;  p += (size_t)N * sizeof(float);
    float* s2D   = (float*)p;  p += (size_t)N * sizeof(float);
    int* cnt8    = (int*)p;    p += (size_t)8 * N * 4 * sizeof(int);    // [xcd][node] 16B stride
    int* elist8  = (int*)p;    p += (size_t)8 * N * NSL * sizeof(int);  // [xcd][node][NSL]

    int countBlocks = (E + 4095) / 4096;             // 16 edges per thread
    int prepBlocks  = (F_IN * C1 + C1 * C2) / 256;   // 192
    int xprepBlocks = (N + 3) / 4;

    hipMemsetAsync(cnt8, 0, (size_t)8 * N * 4 * sizeof(int), stream);
    k_init<<<5, 256, 0, stream>>>(W1, aS1, aD1, b2, Wc, bc, atS, atD, cW);
    k_edges_prep<<<countBlocks + prepBlocks + xprepBlocks, 256, 0, stream>>>(
        esrc, edst, cnt8, elist8, E, N, countBlocks, prepBlocks,
        W1, W2, W1T, W2T, x, atS, atD, xh, s1S, s1D);

    k_aggr1<<<(N + 3) / 4, 256, 0, stream>>>(elist8, cnt8, s1S, s1D, xh, agg, N);
    k_gemm12<<<(N + 63) / 64, 256, 0, stream>>>(agg, W1T, b1, W2T, aS2, aD2, Wc, z2, s2S, s2D, N);
    k_aggr2<<<(N + 3) / 4, 256, 0, stream>>>(elist8, cnt8, s2S, s2D, z2, cW, out, N);
}

// Round 18
// 158.814 us; speedup vs baseline: 1.0896x; 1.0896x over previous
//
#include <hip/hip_runtime.h>
#include <hip/hip_fp16.h>
#include <math.h>

#define F_IN 128
#define C1 256   // HEADS*HID
#define NH1 4
#define C2 64
#define CSH 4    // cnt stride shift: 16 ints = 64B line per counter

typedef __attribute__((ext_vector_type(8))) _Float16 f16x8;
typedef __attribute__((ext_vector_type(4))) float f32x4;
typedef __attribute__((ext_vector_type(2))) float f32x2;

__device__ __forceinline__ float lrelu(float x) { return x >= 0.f ? x : 0.2f * x; }
__device__ __forceinline__ float elu(float x) { return x > 0.f ? x : expm1f(x); }
__device__ __forceinline__ int rli(int v, int j) { return __builtin_amdgcn_readlane(v, j); }

// packed 2xf32 FMA: acc += a * b (per 32-bit half)
__device__ __forceinline__ void pkfma(f32x2& acc, f32x2 a, f32x2 b) {
    asm("v_pk_fma_f32 %0, %1, %2, %0" : "+v"(acc) : "v"(a), "v"(b));
}

struct __align__(8) H4 { __half2 a, b; };

// ---------------- k_init: zero counters (stride-16) + atS/atD + cW ----------------
__global__ __launch_bounds__(256) void k_init(int* __restrict__ cnt, int N, int zBlocks,
                                              const float* __restrict__ W1,
                                              const float* __restrict__ aS1,
                                              const float* __restrict__ aD1,
                                              const float* __restrict__ b2,
                                              const float* __restrict__ Wc,
                                              const float* __restrict__ bc,
                                              float* __restrict__ atS,
                                              float* __restrict__ atD,
                                              float* __restrict__ cW) {
    int b = blockIdx.x;
    if (b < zBlocks) {
        int i = b * 256 + threadIdx.x;
        if (i < N) cnt[(size_t)i << CSH] = 0;
    } else if (b < zBlocks + 4) {
        int t3 = (b - zBlocks) * 256 + threadIdx.x;
        bool isD = t3 >= 512;
        int r = t3 & 511;
        int h = r >> 7, k = r & 127;
        const float* a = isD ? aD1 : aS1;
        float s = 0.f;
        for (int c = 0; c < 64; ++c) s += W1[(size_t)k * C1 + h * 64 + c] * a[h * 64 + c];
        (isD ? atD : atS)[h * 128 + k] = s;
    } else if (threadIdx.x < 2) {
        int j = threadIdx.x;
        float s = bc[j];
        for (int c = 0; c < 64; ++c) s += b2[c] * Wc[c * 2 + j];
        cW[j] = s;
    }
}

// ---------------- k1: bucketed edge pass (16 edges/thread, 2 pipelined 8-groups) ----
// Real edges land at slot p+1 (slot 0 = implicit self-loop).
__global__ __launch_bounds__(256) void k_edges_prep(
    const int* __restrict__ esrc, const int* __restrict__ edst,
    int* __restrict__ cnt, int* __restrict__ elist, int E, int N,
    int countBlocks, int prepBlocks,
    const float* __restrict__ W1, const float* __restrict__ W2,
    __half* __restrict__ W1T, __half* __restrict__ W2T,
    const float* __restrict__ x, const float* __restrict__ atS,
    const float* __restrict__ atD, __half* __restrict__ xh,
    float* __restrict__ sS, float* __restrict__ sD) {
    int b = blockIdx.x;
    if (b < countBlocks) {
        int base = b * 4096 + threadIdx.x;
        int sv[16], dv[16], pv[16];
#pragma unroll
        for (int k = 0; k < 16; ++k) {      // coalesced edge loads
            int e = base + k * 256;
            int ss = 0, dd = -1;
            if (e < E) { ss = esrc[e]; dd = edst[e]; }
            sv[k] = ss; dv[k] = dd;
        }
#pragma unroll
        for (int k = 0; k < 8; ++k)         // atomics group A
            pv[k] = (dv[k] >= 0) ? atomicAdd(&cnt[(size_t)dv[k] << CSH], 1) : 63;
#pragma unroll
        for (int k = 8; k < 16; ++k)        // atomics group B (16 in flight)
            pv[k] = (dv[k] >= 0) ? atomicAdd(&cnt[(size_t)dv[k] << CSH], 1) : 63;
#pragma unroll
        for (int k = 0; k < 8; ++k)         // scatter A (B atomics still flying)
            if (dv[k] >= 0 && pv[k] < 63) elist[(dv[k] << 6) + pv[k] + 1] = sv[k];
#pragma unroll
        for (int k = 8; k < 16; ++k)        // scatter B
            if (dv[k] >= 0 && pv[k] < 63) elist[(dv[k] << 6) + pv[k] + 1] = sv[k];
    } else if (b < countBlocks + prepBlocks) {
        int tid = (b - countBlocks) * 256 + threadIdx.x;
        if (tid < F_IN * C1) {
            int k = tid >> 8, n = tid & 255;
            W1T[n * F_IN + k] = __float2half(W1[tid]);
        }
        int t2 = tid - F_IN * C1;
        if (t2 >= 0 && t2 < C1 * C2) {
            int k = t2 >> 6, n = t2 & 63;
            W2T[n * C1 + k] = __float2half(W2[t2]);
        }
    } else {
        int n = (b - countBlocks - prepBlocks) * 4 + (threadIdx.x >> 6);
        if (n >= N) return;
        int l = threadIdx.x & 63;
        float2 xv = *(const float2*)(x + (size_t)n * F_IN + l * 2);
        *(__half2*)(xh + (size_t)n * F_IN + l * 2) = __floats2half2_rn(xv.x, xv.y);
        float p[8];
#pragma unroll
        for (int h = 0; h < 4; ++h) {
            float2 a = *(const float2*)(atS + h * 128 + l * 2);
            float2 bb = *(const float2*)(atD + h * 128 + l * 2);
            p[h]     = xv.x * a.x + xv.y * a.y;
            p[4 + h] = xv.x * bb.x + xv.y * bb.y;
        }
#pragma unroll
        for (int off = 1; off < 64; off <<= 1) {
#pragma unroll
            for (int j = 0; j < 8; ++j) p[j] += __shfl_xor(p[j], off, 64);
        }
        if (l == 0) {
            *(float4*)(sS + n * 4) = make_float4(p[0], p[1], p[2], p[3]);
            *(float4*)(sD + n * 4) = make_float4(p[4], p[5], p[6], p[7]);
        }
    }
}

// ---------------- layer-1 aggregation in x-space, fused softmax (r7 structure) ----------------
__global__ __launch_bounds__(256) void k_aggr1(const int* __restrict__ elist,
                                               const int* __restrict__ cnt,
                                               const float* __restrict__ sS,
                                               const float* __restrict__ sD,
                                               const __half* __restrict__ xh,
                                               __half* __restrict__ agg, int N) {
    __shared__ __align__(16) float wA[4][64][8];   // {wx,wx,wy,wy,wz,wz,ww,ww}
    int wv = threadIdx.x >> 6, l = threadIdx.x & 63;
    int d = blockIdx.x * 4 + wv;
    if (d >= N) return;
    int len = cnt[(size_t)d << CSH] + 1; if (len > 64) len = 64;
    int base = d << 6;
    float4 sd4 = *(const float4*)(sD + d * 4);
    const __half* xb = xh + l * 2;
    f32x2 a0 = {0.f, 0.f}, a1 = {0.f, 0.f}, a2 = {0.f, 0.f}, a3 = {0.f, 0.f};
    float4 den = {0.f, 0.f, 0.f, 0.f};
    int sl = 0;
    float4 w = {0.f, 0.f, 0.f, 0.f};
    if (l < len) {
        sl = (l == 0) ? d : elist[base + l];   // implicit self-loop at slot 0
        float4 s4 = *(const float4*)(sS + sl * 4);
        w.x = __expf(lrelu(s4.x + sd4.x));
        w.y = __expf(lrelu(s4.y + sd4.y));
        w.z = __expf(lrelu(s4.z + sd4.z));
        w.w = __expf(lrelu(s4.w + sd4.w));
        den.x = w.x; den.y = w.y; den.z = w.z; den.w = w.w;
    }
    *(float4*)&wA[wv][l][0] = make_float4(w.x, w.x, w.y, w.y);
    *(float4*)&wA[wv][l][4] = make_float4(w.z, w.z, w.w, w.w);
    __builtin_amdgcn_wave_barrier();   // in-wave LDS RAW ordering
    int jm = (len + 3) & ~3;           // zero-padded slots: branch-free
    for (int j = 0; j < jm; j += 4) {
#pragma unroll
        for (int u = 0; u < 4; ++u) {
            int s = rli(sl, j + u);
            f32x4 q0 = *(const f32x4*)&wA[wv][j + u][0];   // uniform broadcast
            f32x4 q1 = *(const f32x4*)&wA[wv][j + u][4];
            float2 f = __half22float2(*(const __half2*)(xb + ((size_t)(unsigned)s << 7)));
            f32x2 fv = {f.x, f.y};
            pkfma(a0, fv, f32x2{q0[0], q0[1]});
            pkfma(a1, fv, f32x2{q0[2], q0[3]});
            pkfma(a2, fv, f32x2{q1[0], q1[1]});
            pkfma(a3, fv, f32x2{q1[2], q1[3]});
        }
    }
#pragma unroll
    for (int off = 1; off < 64; off <<= 1) {
        den.x += __shfl_xor(den.x, off, 64);
        den.y += __shfl_xor(den.y, off, 64);
        den.z += __shfl_xor(den.z, off, 64);
        den.w += __shfl_xor(den.w, off, 64);
    }
    float i0 = 1.f / (den.x + 1e-16f), i1 = 1.f / (den.y + 1e-16f);
    float i2 = 1.f / (den.z + 1e-16f), i3 = 1.f / (den.w + 1e-16f);
    __half2* ag = (__half2*)(agg + (size_t)d * 512);
    ag[0 * 64 + l] = __floats2half2_rn(a0[0] * i0, a0[1] * i0);
    ag[1 * 64 + l] = __floats2half2_rn(a1[0] * i1, a1[1] * i1);
    ag[2 * 64 + l] = __floats2half2_rn(a2[0] * i2, a2[1] * i2);
    ag[3 * 64 + l] = __floats2half2_rn(a3[0] * i3, a3[1] * i3);
}

// ---------------- fused GEMM1 (per-head) + GEMM2 + classifier-projection z ----------------
// z[n][2] = h2[n] @ Wc computed from fp32 accumulators; h2 never materialized.
__global__ __launch_bounds__(256) void k_gemm12(
    const __half* __restrict__ agg, const __half* __restrict__ W1T,
    const float* __restrict__ b1, const __half* __restrict__ W2T,
    const float* __restrict__ aS, const float* __restrict__ aD,
    const float* __restrict__ Wc,
    float* __restrict__ z2, float* __restrict__ sS, float* __restrict__ sD, int N) {
    __shared__ __align__(16) char smem[65536];
    __half* As  = (__half*)smem;             // [64][128] granule-swizzled (16KB)
    __half* Bs1 = (__half*)(smem + 16384);   // [64][128] (16KB)
    __half* Bs2 = (__half*)smem;             // [64][256] aliases As+Bs1 (32KB)
    __half* o1L = (__half*)(smem + 32768);   // [64][256] swizzled o1 tile (32KB)
    int t = threadIdx.x;
    int rowBase = blockIdx.x * 64;
    int lane = t & 63, wv = t >> 6;
    int lm = lane & 15, lk = lane >> 4;
    int rA = wv * 16 + lm;
    int row = rowBase + rA;

    // phase A: o1 = ELU(agg @ W1 + b1), one 64-col block per head
    for (int h = 0; h < 4; ++h) {
        __syncthreads();
        {   // stage As <- agg head h
            int r = t >> 2;
            const uint4* src = (const uint4*)(agg + (size_t)(rowBase + r) * 512 + h * 128);
#pragma unroll
            for (int j = 0; j < 4; ++j) {
                int g = (t & 3) * 4 + j;
                uint4 v = {0, 0, 0, 0};
                if (rowBase + r < N) v = src[g];
                *(uint4*)&As[r * 128 + (g ^ (r & 7)) * 8] = v;
            }
        }
        {   // stage Bs1 <- W1T rows h*64..+63
            int r = t >> 2;
            const uint4* src = (const uint4*)(W1T + (size_t)(h * 64 + r) * 128);
#pragma unroll
            for (int j = 0; j < 4; ++j) {
                int g = (t & 3) * 4 + j;
                *(uint4*)&Bs1[r * 128 + (g ^ (r & 7)) * 8] = src[g];
            }
        }
        __syncthreads();
        f32x4 acc[4];
#pragma unroll
        for (int nt = 0; nt < 4; ++nt) acc[nt] = f32x4{0.f, 0.f, 0.f, 0.f};
#pragma unroll
        for (int kt = 0; kt < 4; ++kt) {
            int gs = ((kt * 4 + lk) ^ (lm & 7)) * 8;
            f16x8 af = *(const f16x8*)&As[rA * 128 + gs];
#pragma unroll
            for (int nt = 0; nt < 4; ++nt) {
                f16x8 bf = *(const f16x8*)&Bs1[(nt * 16 + lm) * 128 + gs];
                acc[nt] = __builtin_amdgcn_mfma_f32_16x16x32_f16(bf, af, acc[nt], 0, 0, 0);
            }
        }
#pragma unroll
        for (int nt = 0; nt < 4; ++nt) {   // epilogue -> swizzled LDS tile
            int c = h * 64 + nt * 16 + lk * 4;
            float4 bb = *(const float4*)(b1 + c);
            H4 hv;
            hv.a = __floats2half2_rn(elu(acc[nt][0] + bb.x), elu(acc[nt][1] + bb.y));
            hv.b = __floats2half2_rn(elu(acc[nt][2] + bb.z), elu(acc[nt][3] + bb.w));
            int g = c >> 3;
            int gs2 = (g & ~7) | ((g & 7) ^ (rA & 7));
            *(H4*)((char*)o1L + rA * 512 + gs2 * 16 + (c & 7) * 2) = hv;
        }
    }
    __syncthreads();   // o1L complete; As/Bs1 consumers done
    {   // stage Bs2 <- W2T [64][256]
        int n = t & 63, gb = (t >> 6) * 8;
        const uint4* src = (const uint4*)(W2T + (size_t)n * C1);
#pragma unroll
        for (int j = 0; j < 8; ++j) {
            int g = gb + j;
            int gs = (g & ~7) | ((g & 7) ^ (n & 7));
            *(uint4*)&Bs2[n * 256 + gs * 8] = src[g];
        }
    }
    __syncthreads();

    // phase B: h2 = o1 @ W2 (K=256), fused scores + z = h2 @ Wc
    f32x4 acc2[4];
#pragma unroll
    for (int nt = 0; nt < 4; ++nt) acc2[nt] = f32x4{0.f, 0.f, 0.f, 0.f};
#pragma unroll
    for (int kt2 = 0; kt2 < 8; ++kt2) {
        int g = kt2 * 4 + lk;
        int gs = (g & ~7) | ((g & 7) ^ (lm & 7));   // rA&7 == lm&7
        f16x8 af = *(const f16x8*)&o1L[rA * 256 + gs * 8];
#pragma unroll
        for (int nt = 0; nt < 4; ++nt) {
            f16x8 bf = *(const f16x8*)&Bs2[(nt * 16 + lm) * 256 + gs * 8];
            acc2[nt] = __builtin_amdgcn_mfma_f32_16x16x32_f16(bf, af, acc2[nt], 0, 0, 0);
        }
    }
    float ps = 0.f, pd = 0.f, z0 = 0.f, z1 = 0.f;
#pragma unroll
    for (int nt = 0; nt < 4; ++nt) {
        int cbase = nt * 16 + lk * 4;
        float a0 = acc2[nt][0], a1 = acc2[nt][1], a2 = acc2[nt][2], a3 = acc2[nt][3];
        float4 s4 = *(const float4*)(aS + cbase);
        float4 d4 = *(const float4*)(aD + cbase);
        ps += a0 * s4.x + a1 * s4.y + a2 * s4.z + a3 * s4.w;
        pd += a0 * d4.x + a1 * d4.y + a2 * d4.z + a3 * d4.w;
        float4 w0 = *(const float4*)(Wc + cbase * 2);       // cols cbase, cbase+1
        float4 w1 = *(const float4*)(Wc + cbase * 2 + 4);   // cols cbase+2, cbase+3
        z0 += a0 * w0.x + a1 * w0.z + a2 * w1.x + a3 * w1.z;
        z1 += a0 * w0.y + a1 * w0.w + a2 * w1.y + a3 * w1.w;
    }
    ps += __shfl_xor(ps, 16, 64); ps += __shfl_xor(ps, 32, 64);
    pd += __shfl_xor(pd, 16, 64); pd += __shfl_xor(pd, 32, 64);
    z0 += __shfl_xor(z0, 16, 64); z0 += __shfl_xor(z0, 32, 64);
    z1 += __shfl_xor(z1, 16, 64); z1 += __shfl_xor(z1, 32, 64);
    if (lk == 0 && row < N) {
        sS[row] = ps; sD[row] = pd;
        *(float2*)(z2 + 2 * row) = make_float2(z0, z1);
    }
}

// ---------------- layer-2 aggregation on z (8B/edge) + fused classifier ----------------
__global__ __launch_bounds__(256) void k_aggr2(const int* __restrict__ elist,
                                               const int* __restrict__ cnt,
                                               const float* __restrict__ sS,
                                               const float* __restrict__ sD,
                                               const float* __restrict__ z2,
                                               const float* __restrict__ cW,
                                               float* __restrict__ out, int N) {
    int wv = threadIdx.x >> 6, l = threadIdx.x & 63;
    int d = blockIdx.x * 4 + wv;
    if (d >= N) return;
    int len = cnt[(size_t)d << CSH] + 1; if (len > 64) len = 64;
    float sdd = sD[d];
    float den = 0.f, nx = 0.f, ny = 0.f;
    if (l < len) {
        int sl = (l == 0) ? d : elist[(d << 6) + l];   // implicit self-loop at slot 0
        float2 z = *(const float2*)(z2 + 2 * sl);
        float w = __expf(lrelu(sS[sl] + sdd));
        den = w; nx = w * z.x; ny = w * z.y;
    }
#pragma unroll
    for (int off = 1; off < 64; off <<= 1) {
        den += __shfl_xor(den, off, 64);
        nx  += __shfl_xor(nx,  off, 64);
        ny  += __shfl_xor(ny,  off, 64);
    }
    if (l == 0) {
        float inv = 1.f / (den + 1e-16f);
        out[d * 2 + 0] = nx * inv + cW[0];
        out[d * 2 + 1] = ny * inv + cW[1];
    }
}

extern "C" void kernel_launch(void* const* d_in, const int* in_sizes, int n_in,
                              void* d_out, int out_size, void* d_ws, size_t ws_size,
                              hipStream_t stream) {
    const float* x   = (const float*)d_in[0];
    const int*   ei  = (const int*)d_in[1];
    const float* W1  = (const float*)d_in[2];
    const float* aS1 = (const float*)d_in[3];
    const float* aD1 = (const float*)d_in[4];
    const float* b1  = (const float*)d_in[5];
    const float* W2  = (const float*)d_in[6];
    const float* aS2 = (const float*)d_in[7];
    const float* aD2 = (const float*)d_in[8];
    const float* b2  = (const float*)d_in[9];
    const float* Wc  = (const float*)d_in[10];
    const float* bc  = (const float*)d_in[11];
    float* out = (float*)d_out;

    int N = in_sizes[0] / F_IN;
    int E = in_sizes[1] / 2;
    const int* esrc = ei;
    const int* edst = ei + E;

    char* p = (char*)d_ws;
    __half* agg  = (__half*)p; p += (size_t)N * 512 * sizeof(__half);
    __half* xh   = (__half*)p; p += (size_t)N * F_IN * sizeof(__half);
    float* z2    = (float*)p;  p += (size_t)N * 2 * sizeof(float);
    float* s1S   = (float*)p;  p += (size_t)N * NH1 * sizeof(float);
    float* s1D   = (float*)p;  p += (size_t)N * NH1 * sizeof(float);
    __half* W1T  = (__half*)p; p += (size_t)C1 * F_IN * sizeof(__half);
    __half* W2T  = (__half*)p; p += (size_t)C2 * C1 * sizeof(__half);
    float* atS   = (float*)p;  p += 512 * sizeof(float);
    float* atD   = (float*)p;  p += 512 * sizeof(float);
    float* cW    = (float*)p;  p += 2 * sizeof(float);
    float* s2S   = (float*)p;  p += (size_t)N * sizeof(float);
    float* s2D   = (float*)p;  p += (size_t)N * sizeof(float);
    int* cnt     = (int*)p;    p += ((size_t)N << CSH) * sizeof(int);   // 64B per counter
    int* elist   = (int*)p;    p += (size_t)N * 64 * sizeof(int);

    int zBlocks     = (N + 255) / 256;
    int countBlocks = (E + 4095) / 4096;             // 16 edges per thread
    int prepBlocks  = (F_IN * C1 + C1 * C2) / 256;   // 192
    int xprepBlocks = (N + 3) / 4;

    k_init<<<zBlocks + 5, 256, 0, stream>>>(cnt, N, zBlocks, W1, aS1, aD1, b2, Wc, bc,
                                            atS, atD, cW);
    k_edges_prep<<<countBlocks + prepBlocks + xprepBlocks, 256, 0, stream>>>(
        esrc, edst, cnt, elist, E, N, countBlocks, prepBlocks,
        W1, W2, W1T, W2T, x, atS, atD, xh, s1S, s1D);

    k_aggr1<<<(N + 3) / 4, 256, 0, stream>>>(elist, cnt, s1S, s1D, xh, agg, N);
    k_gemm12<<<(N + 63) / 64, 256, 0, stream>>>(agg, W1T, b1, W2T, aS2, aD2, Wc, z2, s2S, s2D, N);
    k_aggr2<<<(N + 3) / 4, 256, 0, stream>>>(elist, cnt, s2S, s2D, z2, cW, out, N);
}